// Round 3
// baseline (475.775 us; speedup 1.0000x reference)
//
#include <hip/hip_runtime.h>

// ContextAttentionBlock fused kernel for gfx950.
// Per (b,h) row-strip (2048 strips of [128x128]): everything in LDS with
// bf16 MFMA (32x32x16), fp32 accum. Shortcut conv folded into the output
// projection (w_sc @ Wo1 precomputed). 1024 threads = 16 waves, each wave
// owns one 32x32 output tile per phase.
// NOTE: __launch_bounds__ 2nd arg behaves CUDA-style here (min WORKGROUPS/CU):
// (1024,4) clamped VGPRs to 64 -> massive spills (R2: FETCH 849MB). (1024,1)
// gives the 128-VGPR cap that our ~90-VGPR state fits without spilling.

typedef __bf16 bf16x8 __attribute__((ext_vector_type(8)));
typedef float f32x16 __attribute__((ext_vector_type(16)));
typedef unsigned short u16x4 __attribute__((ext_vector_type(4)));
typedef unsigned short ushort_t;

__device__ __forceinline__ unsigned short f2bf(float x) {
    unsigned int u = __float_as_uint(x);
    u += 0x7fffu + ((u >> 16) & 1u);   // round-to-nearest-even
    return (unsigned short)(u >> 16);
}
__device__ __forceinline__ float bf2f(unsigned short h) {
    return __uint_as_float(((unsigned int)h) << 16);
}
// byte offset inside a [128][128] bf16 buffer (256 B rows).
// XOR of row bits into byte-offset bits 4..7 spreads 32-consecutive-row
// column accesses over 16 distinct 16B slots -> 2-way bank aliasing (free).
__device__ __forceinline__ int swz(int row, int cb) {
    return (row << 8) + (cb ^ ((row & 15) << 4));
}
__device__ __forceinline__ float sigm(float t) {
    return 1.0f / (1.0f + __expf(-t));
}

// ---------------- pre-pass 1: combined shortcut weight -----------------
// Wsc2[k][n] = sum_c w_sc[k][c] * w_out[128+c][n]
// bout2[n]   = b_out[n] + sum_c b_sc[c] * w_out[128+c][n]
__global__ void prep_combine(const float* __restrict__ w_sc,
                             const float* __restrict__ b_sc,
                             const float* __restrict__ w_out,
                             const float* __restrict__ b_out,
                             float* __restrict__ wsc2,
                             float* __restrict__ bout2) {
    int k = blockIdx.x;      // 0..127
    int n = threadIdx.x;     // 0..127
    float acc = 0.f;
    for (int c = 0; c < 128; ++c)
        acc += w_sc[k * 128 + c] * w_out[(128 + c) * 128 + n];
    wsc2[k * 128 + n] = acc;
    if (k == 0) {
        float b = b_out[n];
        for (int c = 0; c < 128; ++c)
            b += b_sc[c] * w_out[(128 + c) * 128 + n];
        bout2[n] = b;
    }
}

// ---------------- pre-pass 2: pack weights into MFMA B-frag order ------
// pack[((nt*8+kk)*64+lane)*8 + j] = bf16( W[kk*16 + 8*(lane>>5) + j][nt*32 + (lane&31)] )
__global__ void prep_pack(const float* __restrict__ wth,
                          const float* __restrict__ wph,
                          const float* __restrict__ wg,
                          const float* __restrict__ wout,
                          const float* __restrict__ wsc2,
                          ushort_t* __restrict__ packs) {
    int m = blockIdx.x;
    const float* src;
    int rowoff = 0;
    if (m == 0) src = wth;
    else if (m == 1) src = wph;
    else if (m == 2) src = wg;
    else if (m == 3) { src = wout; rowoff = 0; }
    else if (m == 4) { src = wout; rowoff = 256; }
    else src = wsc2;
    ushort_t* dst = packs + m * 16384;
    for (int i = threadIdx.x; i < 16384; i += blockDim.x) {
        int j = i & 7;
        int lane = (i >> 3) & 63;
        int kk = (i >> 9) & 7;
        int nt = i >> 12;
        int k = kk * 16 + ((lane >> 5) << 3) + j;
        int n = nt * 32 + (lane & 31);
        dst[i] = f2bf(src[(rowoff + k) * 128 + n]);
    }
}

// ---------------- main fused kernel ------------------------------------
#define XB  0
#define FPB 32768
#define FPT 65536
#define FGT 98304

__global__ __launch_bounds__(1024, 1)
void cab_main(const float* __restrict__ x,
              const float* __restrict__ b_theta,
              const float* __restrict__ b_phi,
              const float* __restrict__ b_g,
              const ushort_t* __restrict__ packs,
              const float* __restrict__ bout2,
              float* __restrict__ out,
              int nstrips, int spb) {
    __shared__ __align__(16) char lds[131072];

    const int tid = threadIdx.x;
    const int l   = tid & 63;
    const int wv  = tid >> 6;          // 0..15
    const int ct  = wv & 3;            // tile col (0..3)
    const int rt  = wv >> 2;           // tile row (0..3)
    const int ln  = l & 31;
    const int lh  = l >> 5;
    const int colg = ct * 32 + ln;     // this wave's output column
    const int m0   = rt * 32;          // this wave's output row base

    const ushort_t* pTH = packs;
    const ushort_t* pPH = packs + 16384;
    const ushort_t* pG  = packs + 2 * 16384;
    const ushort_t* pO0 = packs + 3 * 16384;
    const ushort_t* pO2 = packs + 4 * 16384;
    const ushort_t* pS2 = packs + 5 * 16384;

    const float biasTH = b_theta[colg];
    const float biasPH = b_phi[colg];
    const float biasG  = b_g[colg];
    const float biasO  = bout2[colg];

    const int s0 = blockIdx.x * spb;
    if (s0 >= nstrips) return;
    const float4* x4 = (const float4*)x;

    float4 pf[4];
    // preload + stage first strip: thread covers 4 float4 = 16 floats
    {
        long base = (long)s0 * 4096;
#pragma unroll
        for (int q = 0; q < 4; ++q) pf[q] = x4[base + q * 1024 + tid];
    }
#pragma unroll
    for (int q = 0; q < 4; ++q) {
        int row = q * 32 + (tid >> 5);
        int cb = (tid & 31) * 8;
        u16x4 v;
        v[0] = f2bf(pf[q].x); v[1] = f2bf(pf[q].y);
        v[2] = f2bf(pf[q].z); v[3] = f2bf(pf[q].w);
        *(u16x4*)(lds + XB + swz(row, cb)) = v;
    }
    __syncthreads();

    for (int it = 0; it < spb; ++it) {
        const int s = s0 + it;
        f32x16 acc;

        // ===== B1: f_phi = xb @ w_phi + b  -> FPB (row-major) + FPT ([c][w])
#pragma unroll
        for (int i = 0; i < 16; ++i) acc[i] = 0.f;
#pragma unroll
        for (int kk = 0; kk < 8; ++kk) {
            bf16x8 b = *(const bf16x8*)(pPH + (((ct * 8 + kk) * 64 + l) << 3));
            bf16x8 a = *(const bf16x8*)(lds + XB + swz(m0 + ln, kk * 32 + lh * 16));
            acc = __builtin_amdgcn_mfma_f32_32x32x16_bf16(a, b, acc, 0, 0, 0);
        }
#pragma unroll
        for (int r = 0; r < 16; ++r) {
            int row = m0 + (r & 3) + ((r >> 2) << 3) + (lh << 2);
            *(ushort_t*)(lds + FPB + swz(row, colg * 2)) = f2bf(acc[r] + biasPH);
        }
#pragma unroll
        for (int q = 0; q < 4; ++q) {
            int w0 = m0 + (q << 3) + (lh << 2);
            u16x4 v;
#pragma unroll
            for (int e = 0; e < 4; ++e) v[e] = f2bf(acc[q * 4 + e] + biasPH);
            *(u16x4*)(lds + FPT + swz(colg, w0 * 2)) = v;
        }

        // ===== B2: f_g = xb @ w_g + b -> FGT ([c][w])
#pragma unroll
        for (int i = 0; i < 16; ++i) acc[i] = 0.f;
#pragma unroll
        for (int kk = 0; kk < 8; ++kk) {
            bf16x8 b = *(const bf16x8*)(pG + (((ct * 8 + kk) * 64 + l) << 3));
            bf16x8 a = *(const bf16x8*)(lds + XB + swz(m0 + ln, kk * 32 + lh * 16));
            acc = __builtin_amdgcn_mfma_f32_32x32x16_bf16(a, b, acc, 0, 0, 0);
        }
#pragma unroll
        for (int q = 0; q < 4; ++q) {
            int w0 = m0 + (q << 3) + (lh << 2);
            u16x4 v;
#pragma unroll
            for (int e = 0; e < 4; ++e) v[e] = f2bf(acc[q * 4 + e] + biasG);
            *(u16x4*)(lds + FGT + swz(colg, w0 * 2)) = v;
        }
        __syncthreads();   // (1) FPB/FPT/FGT ready

        // prefetch next strip's x into registers (latency hidden by D/B3/C/E)
        if (it + 1 < spb) {
            long base = (long)(s + 1) * 4096;
#pragma unroll
            for (int q = 0; q < 4; ++q) pf[q] = x4[base + q * 1024 + tid];
        }

        // ===== D: v-logits  D[j][i] = sum_w fp[w][j] * fg[w][i]
#pragma unroll
        for (int i = 0; i < 16; ++i) acc[i] = 0.f;
#pragma unroll
        for (int kk = 0; kk < 8; ++kk) {
            bf16x8 b = *(const bf16x8*)(lds + FGT + swz(colg, kk * 32 + lh * 16));
            bf16x8 a = *(const bf16x8*)(lds + FPT + swz(m0 + ln, kk * 32 + lh * 16));
            acc = __builtin_amdgcn_mfma_f32_32x32x16_bf16(a, b, acc, 0, 0, 0);
        }
        __syncthreads();   // (2) all D reads of FPT/FGT done

        // V epilogue: V[i][j] = sigm(D[j][i]) * x[i][j]  -> overwrite FGT
#pragma unroll
        for (int q = 0; q < 4; ++q) {
            int j0 = m0 + (q << 3) + (lh << 2);
            u16x4 xv = *(const u16x4*)(lds + XB + swz(colg, j0 * 2));
            u16x4 v;
#pragma unroll
            for (int e = 0; e < 4; ++e)
                v[e] = f2bf(sigm(acc[q * 4 + e]) * bf2f(xv[e]));
            *(u16x4*)(lds + FGT + swz(colg, j0 * 2)) = v;
        }

        // ===== B3: f_theta = xb @ w_theta + b -> FPT slot (row-major "ftb")
#pragma unroll
        for (int i = 0; i < 16; ++i) acc[i] = 0.f;
#pragma unroll
        for (int kk = 0; kk < 8; ++kk) {
            bf16x8 b = *(const bf16x8*)(pTH + (((ct * 8 + kk) * 64 + l) << 3));
            bf16x8 a = *(const bf16x8*)(lds + XB + swz(m0 + ln, kk * 32 + lh * 16));
            acc = __builtin_amdgcn_mfma_f32_32x32x16_bf16(a, b, acc, 0, 0, 0);
        }
#pragma unroll
        for (int r = 0; r < 16; ++r) {
            int row = m0 + (r & 3) + ((r >> 2) << 3) + (lh << 2);
            *(ushort_t*)(lds + FPT + swz(row, colg * 2)) = f2bf(acc[r] + biasTH);
        }
        __syncthreads();   // (3) V + ftb ready

        // ===== C: h-logits  D[v][w] = sum_c ft[v][c] * fp[w][c]
#pragma unroll
        for (int i = 0; i < 16; ++i) acc[i] = 0.f;
#pragma unroll
        for (int kk = 0; kk < 8; ++kk) {
            bf16x8 b = *(const bf16x8*)(lds + FPB + swz(colg, kk * 32 + lh * 16));
            bf16x8 a = *(const bf16x8*)(lds + FPT + swz(m0 + ln, kk * 32 + lh * 16));
            acc = __builtin_amdgcn_mfma_f32_32x32x16_bf16(a, b, acc, 0, 0, 0);
        }
        __syncthreads();   // (4) all C reads of FPB/FPT done

        // H epilogue: H[w][v] = sigm(D[v][w]) * x[w][v] -> overwrite FPB
#pragma unroll
        for (int q = 0; q < 4; ++q) {
            int v0 = m0 + (q << 3) + (lh << 2);
            u16x4 xv = *(const u16x4*)(lds + XB + swz(colg, v0 * 2));
            u16x4 v;
#pragma unroll
            for (int e = 0; e < 4; ++e)
                v[e] = f2bf(sigm(acc[q * 4 + e]) * bf2f(xv[e]));
            *(u16x4*)(lds + FPB + swz(colg, v0 * 2)) = v;
        }
        __syncthreads();   // (5) H ready

        // ===== E: out = H @ Wo0 + V @ Wo2 + xb @ Wsc2 + bout2
#pragma unroll
        for (int i = 0; i < 16; ++i) acc[i] = 0.f;
#pragma unroll
        for (int kk = 0; kk < 24; ++kk) {
            const ushort_t* pk = (kk < 8) ? pO0 : ((kk < 16) ? pO2 : pS2);
            const int abase = (kk < 8) ? FPB : ((kk < 16) ? FGT : XB);
            const int kkl = kk & 7;
            bf16x8 b = *(const bf16x8*)(pk + (((ct * 8 + kkl) * 64 + l) << 3));
            bf16x8 a = *(const bf16x8*)(lds + abase + swz(m0 + ln, kkl * 32 + lh * 16));
            acc = __builtin_amdgcn_mfma_f32_32x32x16_bf16(a, b, acc, 0, 0, 0);
        }
        {
            long obase = (long)s * 16384;
#pragma unroll
            for (int r = 0; r < 16; ++r) {
                int row = m0 + (r & 3) + ((r >> 2) << 3) + (lh << 2);
                out[obase + row * 128 + colg] = acc[r] + biasO;
            }
        }
        __syncthreads();   // (6) E's XB reads done

        if (it + 1 < spb) {
#pragma unroll
            for (int q = 0; q < 4; ++q) {
                int row = q * 32 + (tid >> 5);
                int cb = (tid & 31) * 8;
                u16x4 v;
                v[0] = f2bf(pf[q].x); v[1] = f2bf(pf[q].y);
                v[2] = f2bf(pf[q].z); v[3] = f2bf(pf[q].w);
                *(u16x4*)(lds + XB + swz(row, cb)) = v;
            }
            __syncthreads();   // (7) new XB ready
        }
    }
}

extern "C" void kernel_launch(void* const* d_in, const int* in_sizes, int n_in,
                              void* d_out, int out_size, void* d_ws, size_t ws_size,
                              hipStream_t stream) {
    const float* x       = (const float*)d_in[0];
    const float* w_theta = (const float*)d_in[1];
    const float* b_theta = (const float*)d_in[2];
    const float* w_phi   = (const float*)d_in[3];
    const float* b_phi   = (const float*)d_in[4];
    const float* w_g     = (const float*)d_in[5];
    const float* b_g     = (const float*)d_in[6];
    const float* w_sc    = (const float*)d_in[7];
    const float* b_sc    = (const float*)d_in[8];
    const float* w_out   = (const float*)d_in[9];
    const float* b_out   = (const float*)d_in[10];
    float* out = (float*)d_out;

    float* wsc2 = (float*)d_ws;                                        // 128*128 f32
    ushort_t* packs = (ushort_t*)((char*)d_ws + 65536);                // 6*16384 bf16
    float* bout2 = (float*)((char*)d_ws + 65536 + 6 * 16384 * 2);      // 128 f32

    int NS = in_sizes[0] / 16384;   // 2048 strips
    int spb = NS / 256;             // strips per block (8)
    if (spb < 1) spb = 1;
    int grid = (NS + spb - 1) / spb;

    prep_combine<<<128, 128, 0, stream>>>(w_sc, b_sc, w_out, b_out, wsc2, bout2);
    prep_pack<<<6, 256, 0, stream>>>(w_theta, w_phi, w_g, w_out, wsc2, packs);
    cab_main<<<grid, 1024, 0, stream>>>(x, b_theta, b_phi, b_g, packs, bout2, out, NS, spb);
}

// Round 4
// 453.407 us; speedup vs baseline: 1.0493x; 1.0493x over previous
//
#include <hip/hip_runtime.h>

// ContextAttentionBlock fused kernel for gfx950.
// Per (b,h) row-strip (2048 strips of [128x128]): everything in LDS with
// bf16 MFMA (32x32x16), fp32 accum. Shortcut conv folded into the output
// projection (w_sc @ Wo1 precomputed).
//
// Occupancy/VGPR notes (measured R1-R3):
//  - 1024-thr blocks are capped at 64 VGPRs by hipcc regardless of
//    __launch_bounds__ 2nd arg -> massive spills (FETCH 846MB vs 134 ideal).
//  - (512,2) gives 128 VGPRs. Live state here is trimmed to ~90-110 regs:
//    2 accs (32) + chunked prefetch pf[4] (16) + frags + addressing.
//  - LDS rotation: FPT region is dead after phase C, so next strip's x is
//    staged there; XB/FPT roles swap each iteration (no extra stage phase).

typedef __bf16 bf16x8 __attribute__((ext_vector_type(8)));
typedef float f32x16 __attribute__((ext_vector_type(16)));
typedef unsigned short u16x4 __attribute__((ext_vector_type(4)));
typedef unsigned short ushort_t;

__device__ __forceinline__ unsigned short f2bf(float x) {
    unsigned int u = __float_as_uint(x);
    u += 0x7fffu + ((u >> 16) & 1u);   // round-to-nearest-even
    return (unsigned short)(u >> 16);
}
__device__ __forceinline__ float bf2f(unsigned short h) {
    return __uint_as_float(((unsigned int)h) << 16);
}
// byte offset inside a [128][128] bf16 buffer (256 B rows).
// XOR of row bits into byte-offset bits 4..7 spreads 32-consecutive-row
// column accesses over 16 distinct 16B slots -> 2-way bank aliasing (free).
// (R2: conflicts 13.1M -> 2.6M vs the (row&7) variant.)
__device__ __forceinline__ int swz(int row, int cb) {
    return (row << 8) + (cb ^ ((row & 15) << 4));
}
__device__ __forceinline__ float sigm(float t) {
    return 1.0f / (1.0f + __expf(-t));
}

// ---------------- pre-pass 1: combined shortcut weight -----------------
__global__ void prep_combine(const float* __restrict__ w_sc,
                             const float* __restrict__ b_sc,
                             const float* __restrict__ w_out,
                             const float* __restrict__ b_out,
                             float* __restrict__ wsc2,
                             float* __restrict__ bout2) {
    int k = blockIdx.x;      // 0..127
    int n = threadIdx.x;     // 0..127
    float acc = 0.f;
    for (int c = 0; c < 128; ++c)
        acc += w_sc[k * 128 + c] * w_out[(128 + c) * 128 + n];
    wsc2[k * 128 + n] = acc;
    if (k == 0) {
        float b = b_out[n];
        for (int c = 0; c < 128; ++c)
            b += b_sc[c] * w_out[(128 + c) * 128 + n];
        bout2[n] = b;
    }
}

// ---------------- pre-pass 2: pack weights into MFMA B-frag order ------
__global__ void prep_pack(const float* __restrict__ wth,
                          const float* __restrict__ wph,
                          const float* __restrict__ wg,
                          const float* __restrict__ wout,
                          const float* __restrict__ wsc2,
                          ushort_t* __restrict__ packs) {
    int m = blockIdx.x;
    const float* src;
    int rowoff = 0;
    if (m == 0) src = wth;
    else if (m == 1) src = wph;
    else if (m == 2) src = wg;
    else if (m == 3) { src = wout; rowoff = 0; }
    else if (m == 4) { src = wout; rowoff = 256; }
    else src = wsc2;
    ushort_t* dst = packs + m * 16384;
    for (int i = threadIdx.x; i < 16384; i += blockDim.x) {
        int j = i & 7;
        int lane = (i >> 3) & 63;
        int kk = (i >> 9) & 7;
        int nt = i >> 12;
        int k = kk * 16 + ((lane >> 5) << 3) + j;
        int n = nt * 32 + (lane & 31);
        dst[i] = f2bf(src[(rowoff + k) * 128 + n]);
    }
}

// ---------------- main fused kernel ------------------------------------
#define FPB 32768
#define FGT 98304

__global__ __launch_bounds__(512, 2)
void cab_main(const float* __restrict__ x,
              const float* __restrict__ b_theta,
              const float* __restrict__ b_phi,
              const float* __restrict__ b_g,
              const ushort_t* __restrict__ packs,
              const float* __restrict__ bout2,
              float* __restrict__ out,
              int nstrips, int spb) {
    __shared__ __align__(16) char lds[131072];

    const int tid = threadIdx.x;
    const int l   = tid & 63;
    const int wv  = tid >> 6;          // 0..7
    const int ct  = wv & 3;            // tile col (0..3)
    const int rt0 = (wv >> 2) << 1;    // tile rows rt0, rt0+1
    const int ln  = l & 31;
    const int lh  = l >> 5;
    const int colg = ct * 32 + ln;     // this wave's output column

    const ushort_t* pTH = packs;
    const ushort_t* pPH = packs + 16384;
    const ushort_t* pG  = packs + 2 * 16384;
    const ushort_t* pO0 = packs + 3 * 16384;
    const ushort_t* pO2 = packs + 4 * 16384;
    const ushort_t* pS2 = packs + 5 * 16384;

    const float biasTH = b_theta[colg];
    const float biasPH = b_phi[colg];
    const float biasG  = b_g[colg];
    const float biasO  = bout2[colg];

    const int s0 = blockIdx.x * spb;
    if (s0 >= nstrips) return;
    const float4* x4 = (const float4*)x;

    // staging geometry: idx = q*512+tid covers float4 idx -> row=idx>>5,
    // cb = (tid&31)*8 bytes; chunk c covers rows c*64..c*64+63 (q = c*4..c*4+3)
    const int srow = tid >> 5;          // 0..15
    const int scb  = (tid & 31) * 8;    // byte col

    float4 pf[4];

    // initial full stage of strip s0 into region 0
    {
        long base = (long)s0 * 4096;
#pragma unroll
        for (int c = 0; c < 2; ++c) {
#pragma unroll
            for (int q = 0; q < 4; ++q) pf[q] = x4[base + (c * 4 + q) * 512 + tid];
#pragma unroll
            for (int q = 0; q < 4; ++q) {
                int row = c * 64 + q * 16 + srow;
                u16x4 v;
                v[0] = f2bf(pf[q].x); v[1] = f2bf(pf[q].y);
                v[2] = f2bf(pf[q].z); v[3] = f2bf(pf[q].w);
                *(u16x4*)(lds + swz(row, scb)) = v;
            }
        }
    }
    __syncthreads();

    for (int it = 0; it < spb; ++it) {
        const int s = s0 + it;
        // rotating roles: XB holds current x; FPT region doubles as next-XB
        const int XBo  = (it & 1) ? 65536 : 0;
        const int FPTo = 65536 - XBo;
        f32x16 accA, accB;

        // ===== B1: f_phi = xb @ w_phi + b  -> FPB (row-major) + FPT ([c][w])
#pragma unroll
        for (int i = 0; i < 16; ++i) { accA[i] = 0.f; accB[i] = 0.f; }
#pragma unroll
        for (int kk = 0; kk < 8; ++kk) {
            bf16x8 b  = *(const bf16x8*)(pPH + (((ct * 8 + kk) * 64 + l) << 3));
            bf16x8 a0 = *(const bf16x8*)(lds + XBo + swz(rt0 * 32 + ln,      kk * 32 + lh * 16));
            bf16x8 a1 = *(const bf16x8*)(lds + XBo + swz(rt0 * 32 + 32 + ln, kk * 32 + lh * 16));
            accA = __builtin_amdgcn_mfma_f32_32x32x16_bf16(a0, b, accA, 0, 0, 0);
            accB = __builtin_amdgcn_mfma_f32_32x32x16_bf16(a1, b, accB, 0, 0, 0);
        }
#pragma unroll
        for (int t2 = 0; t2 < 2; ++t2) {
            const f32x16& acc = t2 ? accB : accA;
            int m0 = (rt0 + t2) * 32;
#pragma unroll
            for (int r = 0; r < 16; ++r) {
                int row = m0 + (r & 3) + ((r >> 2) << 3) + (lh << 2);
                *(ushort_t*)(lds + FPB + swz(row, colg * 2)) = f2bf(acc[r] + biasPH);
            }
#pragma unroll
            for (int q = 0; q < 4; ++q) {
                int w0 = m0 + (q << 3) + (lh << 2);
                u16x4 v;
#pragma unroll
                for (int e = 0; e < 4; ++e) v[e] = f2bf(acc[q * 4 + e] + biasPH);
                *(u16x4*)(lds + FPTo + swz(colg, w0 * 2)) = v;
            }
        }

        // ===== B2: f_g = xb @ w_g + b -> FGT ([c][w])
#pragma unroll
        for (int i = 0; i < 16; ++i) { accA[i] = 0.f; accB[i] = 0.f; }
#pragma unroll
        for (int kk = 0; kk < 8; ++kk) {
            bf16x8 b  = *(const bf16x8*)(pG + (((ct * 8 + kk) * 64 + l) << 3));
            bf16x8 a0 = *(const bf16x8*)(lds + XBo + swz(rt0 * 32 + ln,      kk * 32 + lh * 16));
            bf16x8 a1 = *(const bf16x8*)(lds + XBo + swz(rt0 * 32 + 32 + ln, kk * 32 + lh * 16));
            accA = __builtin_amdgcn_mfma_f32_32x32x16_bf16(a0, b, accA, 0, 0, 0);
            accB = __builtin_amdgcn_mfma_f32_32x32x16_bf16(a1, b, accB, 0, 0, 0);
        }
#pragma unroll
        for (int t2 = 0; t2 < 2; ++t2) {
            const f32x16& acc = t2 ? accB : accA;
            int m0 = (rt0 + t2) * 32;
#pragma unroll
            for (int q = 0; q < 4; ++q) {
                int w0 = m0 + (q << 3) + (lh << 2);
                u16x4 v;
#pragma unroll
                for (int e = 0; e < 4; ++e) v[e] = f2bf(acc[q * 4 + e] + biasG);
                *(u16x4*)(lds + FGT + swz(colg, w0 * 2)) = v;
            }
        }
        __syncthreads();   // (1) FPB/FPT/FGT ready

        // issue chunk0 of next strip's x (latency hidden by D/V/B3/C)
        if (it + 1 < spb) {
            long base = (long)(s + 1) * 4096;
#pragma unroll
            for (int q = 0; q < 4; ++q) pf[q] = x4[base + q * 512 + tid];
        }

        // ===== D: v-logits  D[j][i] = sum_w fp[w][j] * fg[w][i]
#pragma unroll
        for (int i = 0; i < 16; ++i) { accA[i] = 0.f; accB[i] = 0.f; }
#pragma unroll
        for (int kk = 0; kk < 8; ++kk) {
            bf16x8 b  = *(const bf16x8*)(lds + FGT + swz(colg, kk * 32 + lh * 16));
            bf16x8 a0 = *(const bf16x8*)(lds + FPTo + swz(rt0 * 32 + ln,      kk * 32 + lh * 16));
            bf16x8 a1 = *(const bf16x8*)(lds + FPTo + swz(rt0 * 32 + 32 + ln, kk * 32 + lh * 16));
            accA = __builtin_amdgcn_mfma_f32_32x32x16_bf16(a0, b, accA, 0, 0, 0);
            accB = __builtin_amdgcn_mfma_f32_32x32x16_bf16(a1, b, accB, 0, 0, 0);
        }
        __syncthreads();   // (2) all D reads of FPT/FGT done

        // V epilogue: V[i][j] = sigm(D[j][i]) * x[i][j]  -> overwrite FGT
#pragma unroll
        for (int t2 = 0; t2 < 2; ++t2) {
            const f32x16& acc = t2 ? accB : accA;
            int m0 = (rt0 + t2) * 32;
#pragma unroll
            for (int q = 0; q < 4; ++q) {
                int j0 = m0 + (q << 3) + (lh << 2);
                u16x4 xv = *(const u16x4*)(lds + XBo + swz(colg, j0 * 2));
                u16x4 v;
#pragma unroll
                for (int e = 0; e < 4; ++e)
                    v[e] = f2bf(sigm(acc[q * 4 + e]) * bf2f(xv[e]));
                *(u16x4*)(lds + FGT + swz(colg, j0 * 2)) = v;
            }
        }

        // ===== B3: f_theta = xb @ w_theta + b -> FPT slot (row-major "ftb")
#pragma unroll
        for (int i = 0; i < 16; ++i) { accA[i] = 0.f; accB[i] = 0.f; }
#pragma unroll
        for (int kk = 0; kk < 8; ++kk) {
            bf16x8 b  = *(const bf16x8*)(pTH + (((ct * 8 + kk) * 64 + l) << 3));
            bf16x8 a0 = *(const bf16x8*)(lds + XBo + swz(rt0 * 32 + ln,      kk * 32 + lh * 16));
            bf16x8 a1 = *(const bf16x8*)(lds + XBo + swz(rt0 * 32 + 32 + ln, kk * 32 + lh * 16));
            accA = __builtin_amdgcn_mfma_f32_32x32x16_bf16(a0, b, accA, 0, 0, 0);
            accB = __builtin_amdgcn_mfma_f32_32x32x16_bf16(a1, b, accB, 0, 0, 0);
        }
#pragma unroll
        for (int t2 = 0; t2 < 2; ++t2) {
            const f32x16& acc = t2 ? accB : accA;
            int m0 = (rt0 + t2) * 32;
#pragma unroll
            for (int r = 0; r < 16; ++r) {
                int row = m0 + (r & 3) + ((r >> 2) << 3) + (lh << 2);
                *(ushort_t*)(lds + FPTo + swz(row, colg * 2)) = f2bf(acc[r] + biasTH);
            }
        }
        __syncthreads();   // (3) V + ftb ready

        // ===== C: h-logits  D[v][w] = sum_c ft[v][c] * fp[w][c]
#pragma unroll
        for (int i = 0; i < 16; ++i) { accA[i] = 0.f; accB[i] = 0.f; }
#pragma unroll
        for (int kk = 0; kk < 8; ++kk) {
            bf16x8 b  = *(const bf16x8*)(lds + FPB + swz(colg, kk * 32 + lh * 16));
            bf16x8 a0 = *(const bf16x8*)(lds + FPTo + swz(rt0 * 32 + ln,      kk * 32 + lh * 16));
            bf16x8 a1 = *(const bf16x8*)(lds + FPTo + swz(rt0 * 32 + 32 + ln, kk * 32 + lh * 16));
            accA = __builtin_amdgcn_mfma_f32_32x32x16_bf16(a0, b, accA, 0, 0, 0);
            accB = __builtin_amdgcn_mfma_f32_32x32x16_bf16(a1, b, accB, 0, 0, 0);
        }
        __syncthreads();   // (4) all C reads of FPB/FPT done; FPT region now free

        // write chunk0 of next x into FPT region (= next iteration's XB)
        if (it + 1 < spb) {
#pragma unroll
            for (int q = 0; q < 4; ++q) {
                int row = q * 16 + srow;     // rows 0..63
                u16x4 v;
                v[0] = f2bf(pf[q].x); v[1] = f2bf(pf[q].y);
                v[2] = f2bf(pf[q].z); v[3] = f2bf(pf[q].w);
                *(u16x4*)(lds + FPTo + swz(row, scb)) = v;
            }
            // issue chunk1 loads (latency hidden by H epilogue + E)
            long base = (long)(s + 1) * 4096;
#pragma unroll
            for (int q = 0; q < 4; ++q) pf[q] = x4[base + (4 + q) * 512 + tid];
        }

        // H epilogue: H[w][v] = sigm(D[v][w]) * x[w][v] -> overwrite FPB
#pragma unroll
        for (int t2 = 0; t2 < 2; ++t2) {
            const f32x16& acc = t2 ? accB : accA;
            int m0 = (rt0 + t2) * 32;
#pragma unroll
            for (int q = 0; q < 4; ++q) {
                int v0 = m0 + (q << 3) + (lh << 2);
                u16x4 xv = *(const u16x4*)(lds + XBo + swz(colg, v0 * 2));
                u16x4 v;
#pragma unroll
                for (int e = 0; e < 4; ++e)
                    v[e] = f2bf(sigm(acc[q * 4 + e]) * bf2f(xv[e]));
                *(u16x4*)(lds + FPB + swz(colg, v0 * 2)) = v;
            }
        }
        __syncthreads();   // (5) H ready

        // ===== E: out = H @ Wo0 + V @ Wo2 + xb @ Wsc2 + bout2
#pragma unroll
        for (int i = 0; i < 16; ++i) { accA[i] = 0.f; accB[i] = 0.f; }
#pragma unroll
        for (int kk = 0; kk < 24; ++kk) {
            const ushort_t* pk = (kk < 8) ? pO0 : ((kk < 16) ? pO2 : pS2);
            const int abase = (kk < 8) ? FPB : ((kk < 16) ? FGT : XBo);
            const int kkl = kk & 7;
            bf16x8 b  = *(const bf16x8*)(pk + (((ct * 8 + kkl) * 64 + l) << 3));
            bf16x8 a0 = *(const bf16x8*)(lds + abase + swz(rt0 * 32 + ln,      kkl * 32 + lh * 16));
            bf16x8 a1 = *(const bf16x8*)(lds + abase + swz(rt0 * 32 + 32 + ln, kkl * 32 + lh * 16));
            accA = __builtin_amdgcn_mfma_f32_32x32x16_bf16(a0, b, accA, 0, 0, 0);
            accB = __builtin_amdgcn_mfma_f32_32x32x16_bf16(a1, b, accB, 0, 0, 0);
        }
        {
            long obase = (long)s * 16384;
#pragma unroll
            for (int t2 = 0; t2 < 2; ++t2) {
                const f32x16& acc = t2 ? accB : accA;
                int m0 = (rt0 + t2) * 32;
#pragma unroll
                for (int r = 0; r < 16; ++r) {
                    int row = m0 + (r & 3) + ((r >> 2) << 3) + (lh << 2);
                    out[obase + row * 128 + colg] = acc[r] + biasO;
                }
            }
        }

        // write chunk1 of next x into FPT region (rows 64..127)
        if (it + 1 < spb) {
#pragma unroll
            for (int q = 0; q < 4; ++q) {
                int row = 64 + q * 16 + srow;
                u16x4 v;
                v[0] = f2bf(pf[q].x); v[1] = f2bf(pf[q].y);
                v[2] = f2bf(pf[q].z); v[3] = f2bf(pf[q].w);
                *(u16x4*)(lds + FPTo + swz(row, scb)) = v;
            }
        }
        __syncthreads();   // (6) E's XB reads + next-x staging done
    }
}

extern "C" void kernel_launch(void* const* d_in, const int* in_sizes, int n_in,
                              void* d_out, int out_size, void* d_ws, size_t ws_size,
                              hipStream_t stream) {
    const float* x       = (const float*)d_in[0];
    const float* w_theta = (const float*)d_in[1];
    const float* b_theta = (const float*)d_in[2];
    const float* w_phi   = (const float*)d_in[3];
    const float* b_phi   = (const float*)d_in[4];
    const float* w_g     = (const float*)d_in[5];
    const float* b_g     = (const float*)d_in[6];
    const float* w_sc    = (const float*)d_in[7];
    const float* b_sc    = (const float*)d_in[8];
    const float* w_out   = (const float*)d_in[9];
    const float* b_out   = (const float*)d_in[10];
    float* out = (float*)d_out;

    float* wsc2 = (float*)d_ws;                                        // 128*128 f32
    ushort_t* packs = (ushort_t*)((char*)d_ws + 65536);                // 6*16384 bf16
    float* bout2 = (float*)((char*)d_ws + 65536 + 6 * 16384 * 2);      // 128 f32

    int NS = in_sizes[0] / 16384;   // 2048 strips
    int spb = NS / 256;             // strips per block (8)
    if (spb < 1) spb = 1;
    int grid = (NS + spb - 1) / spb;

    prep_combine<<<128, 128, 0, stream>>>(w_sc, b_sc, w_out, b_out, wsc2, bout2);
    prep_pack<<<6, 256, 0, stream>>>(w_theta, w_phi, w_g, w_out, wsc2, packs);
    cab_main<<<grid, 512, 0, stream>>>(x, b_theta, b_phi, b_g, packs, bout2, out, NS, spb);
}

// Round 5
// 387.962 us; speedup vs baseline: 1.2263x; 1.1687x over previous
//
#include <hip/hip_runtime.h>

// ContextAttentionBlock fused kernel for gfx950.
// Per (b,h) row-strip (2048 strips of [128x128]): everything in LDS with
// bf16 MFMA (32x32x16), fp32 accum. Shortcut conv folded into the output
// projection (w_sc @ Wo1 precomputed).
//
// Occupancy/VGPR notes (measured R1-R4):
//  - 1024-thr blocks are capped at 64 VGPRs regardless of launch_bounds
//    2nd arg -> massive spills (FETCH 846MB vs 134 ideal).
//  - (512,2) gives 128 VGPRs -> still spills ~30 regs (FETCH 502MB):
//    hoisted fragment loads + 2 accs + prefetch exceed 128.
//  - (512,1): 1 block/CU (LDS forces that anyway) = 2 waves/SIMD -> 256-VGPR
//    cap. This round tests that cell.

typedef __bf16 bf16x8 __attribute__((ext_vector_type(8)));
typedef float f32x16 __attribute__((ext_vector_type(16)));
typedef unsigned short u16x4 __attribute__((ext_vector_type(4)));
typedef unsigned short ushort_t;

__device__ __forceinline__ unsigned short f2bf(float x) {
    unsigned int u = __float_as_uint(x);
    u += 0x7fffu + ((u >> 16) & 1u);   // round-to-nearest-even
    return (unsigned short)(u >> 16);
}
__device__ __forceinline__ float bf2f(unsigned short h) {
    return __uint_as_float(((unsigned int)h) << 16);
}
// byte offset inside a [128][128] bf16 buffer (256 B rows).
// XOR of row bits into byte-offset bits 4..7 spreads 32-consecutive-row
// column accesses over 16 distinct 16B slots -> 2-way bank aliasing (free).
// (R2: conflicts 13.1M -> 2.6M vs the (row&7) variant.)
__device__ __forceinline__ int swz(int row, int cb) {
    return (row << 8) + (cb ^ ((row & 15) << 4));
}
__device__ __forceinline__ float sigm(float t) {
    return 1.0f / (1.0f + __expf(-t));
}

// ---------------- pre-pass 1: combined shortcut weight -----------------
__global__ void prep_combine(const float* __restrict__ w_sc,
                             const float* __restrict__ b_sc,
                             const float* __restrict__ w_out,
                             const float* __restrict__ b_out,
                             float* __restrict__ wsc2,
                             float* __restrict__ bout2) {
    int k = blockIdx.x;      // 0..127
    int n = threadIdx.x;     // 0..127
    float acc = 0.f;
    for (int c = 0; c < 128; ++c)
        acc += w_sc[k * 128 + c] * w_out[(128 + c) * 128 + n];
    wsc2[k * 128 + n] = acc;
    if (k == 0) {
        float b = b_out[n];
        for (int c = 0; c < 128; ++c)
            b += b_sc[c] * w_out[(128 + c) * 128 + n];
        bout2[n] = b;
    }
}

// ---------------- pre-pass 2: pack weights into MFMA B-frag order ------
__global__ void prep_pack(const float* __restrict__ wth,
                          const float* __restrict__ wph,
                          const float* __restrict__ wg,
                          const float* __restrict__ wout,
                          const float* __restrict__ wsc2,
                          ushort_t* __restrict__ packs) {
    int m = blockIdx.x;
    const float* src;
    int rowoff = 0;
    if (m == 0) src = wth;
    else if (m == 1) src = wph;
    else if (m == 2) src = wg;
    else if (m == 3) { src = wout; rowoff = 0; }
    else if (m == 4) { src = wout; rowoff = 256; }
    else src = wsc2;
    ushort_t* dst = packs + m * 16384;
    for (int i = threadIdx.x; i < 16384; i += blockDim.x) {
        int j = i & 7;
        int lane = (i >> 3) & 63;
        int kk = (i >> 9) & 7;
        int nt = i >> 12;
        int k = kk * 16 + ((lane >> 5) << 3) + j;
        int n = nt * 32 + (lane & 31);
        dst[i] = f2bf(src[(rowoff + k) * 128 + n]);
    }
}

// ---------------- main fused kernel ------------------------------------
#define FPB 32768
#define FGT 98304

__global__ __launch_bounds__(512, 1)
void cab_main(const float* __restrict__ x,
              const float* __restrict__ b_theta,
              const float* __restrict__ b_phi,
              const float* __restrict__ b_g,
              const ushort_t* __restrict__ packs,
              const float* __restrict__ bout2,
              float* __restrict__ out,
              int nstrips, int spb) {
    __shared__ __align__(16) char lds[131072];

    const int tid = threadIdx.x;
    const int l   = tid & 63;
    const int wv  = tid >> 6;          // 0..7
    const int ct  = wv & 3;            // tile col (0..3)
    const int rt0 = (wv >> 2) << 1;    // tile rows rt0, rt0+1
    const int ln  = l & 31;
    const int lh  = l >> 5;
    const int colg = ct * 32 + ln;     // this wave's output column

    const ushort_t* pTH = packs;
    const ushort_t* pPH = packs + 16384;
    const ushort_t* pG  = packs + 2 * 16384;
    const ushort_t* pO0 = packs + 3 * 16384;
    const ushort_t* pO2 = packs + 4 * 16384;
    const ushort_t* pS2 = packs + 5 * 16384;

    const float biasTH = b_theta[colg];
    const float biasPH = b_phi[colg];
    const float biasG  = b_g[colg];
    const float biasO  = bout2[colg];

    const int s0 = blockIdx.x * spb;
    if (s0 >= nstrips) return;
    const float4* x4 = (const float4*)x;

    // staging geometry: idx = q*512+tid covers float4 idx -> row=idx>>5,
    // cb = (tid&31)*8 bytes; chunk c covers rows c*64..c*64+63 (q = c*4..c*4+3)
    const int srow = tid >> 5;          // 0..15
    const int scb  = (tid & 31) * 8;    // byte col

    float4 pf[4];

    // initial full stage of strip s0 into region 0
    {
        long base = (long)s0 * 4096;
#pragma unroll
        for (int c = 0; c < 2; ++c) {
#pragma unroll
            for (int q = 0; q < 4; ++q) pf[q] = x4[base + (c * 4 + q) * 512 + tid];
#pragma unroll
            for (int q = 0; q < 4; ++q) {
                int row = c * 64 + q * 16 + srow;
                u16x4 v;
                v[0] = f2bf(pf[q].x); v[1] = f2bf(pf[q].y);
                v[2] = f2bf(pf[q].z); v[3] = f2bf(pf[q].w);
                *(u16x4*)(lds + swz(row, scb)) = v;
            }
        }
    }
    __syncthreads();

    for (int it = 0; it < spb; ++it) {
        const int s = s0 + it;
        // rotating roles: XB holds current x; FPT region doubles as next-XB
        const int XBo  = (it & 1) ? 65536 : 0;
        const int FPTo = 65536 - XBo;
        f32x16 accA, accB;

        // ===== B1: f_phi = xb @ w_phi + b  -> FPB (row-major) + FPT ([c][w])
#pragma unroll
        for (int i = 0; i < 16; ++i) { accA[i] = 0.f; accB[i] = 0.f; }
#pragma unroll
        for (int kk = 0; kk < 8; ++kk) {
            bf16x8 b  = *(const bf16x8*)(pPH + (((ct * 8 + kk) * 64 + l) << 3));
            bf16x8 a0 = *(const bf16x8*)(lds + XBo + swz(rt0 * 32 + ln,      kk * 32 + lh * 16));
            bf16x8 a1 = *(const bf16x8*)(lds + XBo + swz(rt0 * 32 + 32 + ln, kk * 32 + lh * 16));
            accA = __builtin_amdgcn_mfma_f32_32x32x16_bf16(a0, b, accA, 0, 0, 0);
            accB = __builtin_amdgcn_mfma_f32_32x32x16_bf16(a1, b, accB, 0, 0, 0);
        }
#pragma unroll
        for (int t2 = 0; t2 < 2; ++t2) {
            const f32x16& acc = t2 ? accB : accA;
            int m0 = (rt0 + t2) * 32;
#pragma unroll
            for (int r = 0; r < 16; ++r) {
                int row = m0 + (r & 3) + ((r >> 2) << 3) + (lh << 2);
                *(ushort_t*)(lds + FPB + swz(row, colg * 2)) = f2bf(acc[r] + biasPH);
            }
#pragma unroll
            for (int q = 0; q < 4; ++q) {
                int w0 = m0 + (q << 3) + (lh << 2);
                u16x4 v;
#pragma unroll
                for (int e = 0; e < 4; ++e) v[e] = f2bf(acc[q * 4 + e] + biasPH);
                *(u16x4*)(lds + FPTo + swz(colg, w0 * 2)) = v;
            }
        }

        // ===== B2: f_g = xb @ w_g + b -> FGT ([c][w])
#pragma unroll
        for (int i = 0; i < 16; ++i) { accA[i] = 0.f; accB[i] = 0.f; }
#pragma unroll
        for (int kk = 0; kk < 8; ++kk) {
            bf16x8 b  = *(const bf16x8*)(pG + (((ct * 8 + kk) * 64 + l) << 3));
            bf16x8 a0 = *(const bf16x8*)(lds + XBo + swz(rt0 * 32 + ln,      kk * 32 + lh * 16));
            bf16x8 a1 = *(const bf16x8*)(lds + XBo + swz(rt0 * 32 + 32 + ln, kk * 32 + lh * 16));
            accA = __builtin_amdgcn_mfma_f32_32x32x16_bf16(a0, b, accA, 0, 0, 0);
            accB = __builtin_amdgcn_mfma_f32_32x32x16_bf16(a1, b, accB, 0, 0, 0);
        }
#pragma unroll
        for (int t2 = 0; t2 < 2; ++t2) {
            const f32x16& acc = t2 ? accB : accA;
            int m0 = (rt0 + t2) * 32;
#pragma unroll
            for (int q = 0; q < 4; ++q) {
                int w0 = m0 + (q << 3) + (lh << 2);
                u16x4 v;
#pragma unroll
                for (int e = 0; e < 4; ++e) v[e] = f2bf(acc[q * 4 + e] + biasG);
                *(u16x4*)(lds + FGT + swz(colg, w0 * 2)) = v;
            }
        }
        __syncthreads();   // (1) FPB/FPT/FGT ready

        // issue chunk0 of next strip's x (latency hidden by D/V/B3/C)
        if (it + 1 < spb) {
            long base = (long)(s + 1) * 4096;
#pragma unroll
            for (int q = 0; q < 4; ++q) pf[q] = x4[base + q * 512 + tid];
        }

        // ===== D: v-logits  D[j][i] = sum_w fp[w][j] * fg[w][i]
#pragma unroll
        for (int i = 0; i < 16; ++i) { accA[i] = 0.f; accB[i] = 0.f; }
#pragma unroll
        for (int kk = 0; kk < 8; ++kk) {
            bf16x8 b  = *(const bf16x8*)(lds + FGT + swz(colg, kk * 32 + lh * 16));
            bf16x8 a0 = *(const bf16x8*)(lds + FPTo + swz(rt0 * 32 + ln,      kk * 32 + lh * 16));
            bf16x8 a1 = *(const bf16x8*)(lds + FPTo + swz(rt0 * 32 + 32 + ln, kk * 32 + lh * 16));
            accA = __builtin_amdgcn_mfma_f32_32x32x16_bf16(a0, b, accA, 0, 0, 0);
            accB = __builtin_amdgcn_mfma_f32_32x32x16_bf16(a1, b, accB, 0, 0, 0);
        }
        __syncthreads();   // (2) all D reads of FPT/FGT done

        // V epilogue: V[i][j] = sigm(D[j][i]) * x[i][j]  -> overwrite FGT
#pragma unroll
        for (int t2 = 0; t2 < 2; ++t2) {
            const f32x16& acc = t2 ? accB : accA;
            int m0 = (rt0 + t2) * 32;
#pragma unroll
            for (int q = 0; q < 4; ++q) {
                int j0 = m0 + (q << 3) + (lh << 2);
                u16x4 xv = *(const u16x4*)(lds + XBo + swz(colg, j0 * 2));
                u16x4 v;
#pragma unroll
                for (int e = 0; e < 4; ++e)
                    v[e] = f2bf(sigm(acc[q * 4 + e]) * bf2f(xv[e]));
                *(u16x4*)(lds + FGT + swz(colg, j0 * 2)) = v;
            }
        }

        // ===== B3: f_theta = xb @ w_theta + b -> FPT slot (row-major "ftb")
#pragma unroll
        for (int i = 0; i < 16; ++i) { accA[i] = 0.f; accB[i] = 0.f; }
#pragma unroll
        for (int kk = 0; kk < 8; ++kk) {
            bf16x8 b  = *(const bf16x8*)(pTH + (((ct * 8 + kk) * 64 + l) << 3));
            bf16x8 a0 = *(const bf16x8*)(lds + XBo + swz(rt0 * 32 + ln,      kk * 32 + lh * 16));
            bf16x8 a1 = *(const bf16x8*)(lds + XBo + swz(rt0 * 32 + 32 + ln, kk * 32 + lh * 16));
            accA = __builtin_amdgcn_mfma_f32_32x32x16_bf16(a0, b, accA, 0, 0, 0);
            accB = __builtin_amdgcn_mfma_f32_32x32x16_bf16(a1, b, accB, 0, 0, 0);
        }
#pragma unroll
        for (int t2 = 0; t2 < 2; ++t2) {
            const f32x16& acc = t2 ? accB : accA;
            int m0 = (rt0 + t2) * 32;
#pragma unroll
            for (int r = 0; r < 16; ++r) {
                int row = m0 + (r & 3) + ((r >> 2) << 3) + (lh << 2);
                *(ushort_t*)(lds + FPTo + swz(row, colg * 2)) = f2bf(acc[r] + biasTH);
            }
        }
        __syncthreads();   // (3) V + ftb ready

        // ===== C: h-logits  D[v][w] = sum_c ft[v][c] * fp[w][c]
#pragma unroll
        for (int i = 0; i < 16; ++i) { accA[i] = 0.f; accB[i] = 0.f; }
#pragma unroll
        for (int kk = 0; kk < 8; ++kk) {
            bf16x8 b  = *(const bf16x8*)(lds + FPB + swz(colg, kk * 32 + lh * 16));
            bf16x8 a0 = *(const bf16x8*)(lds + FPTo + swz(rt0 * 32 + ln,      kk * 32 + lh * 16));
            bf16x8 a1 = *(const bf16x8*)(lds + FPTo + swz(rt0 * 32 + 32 + ln, kk * 32 + lh * 16));
            accA = __builtin_amdgcn_mfma_f32_32x32x16_bf16(a0, b, accA, 0, 0, 0);
            accB = __builtin_amdgcn_mfma_f32_32x32x16_bf16(a1, b, accB, 0, 0, 0);
        }
        __syncthreads();   // (4) all C reads of FPB/FPT done; FPT region now free

        // write chunk0 of next x into FPT region (= next iteration's XB)
        if (it + 1 < spb) {
#pragma unroll
            for (int q = 0; q < 4; ++q) {
                int row = q * 16 + srow;     // rows 0..63
                u16x4 v;
                v[0] = f2bf(pf[q].x); v[1] = f2bf(pf[q].y);
                v[2] = f2bf(pf[q].z); v[3] = f2bf(pf[q].w);
                *(u16x4*)(lds + FPTo + swz(row, scb)) = v;
            }
            // issue chunk1 loads (latency hidden by H epilogue + E)
            long base = (long)(s + 1) * 4096;
#pragma unroll
            for (int q = 0; q < 4; ++q) pf[q] = x4[base + (4 + q) * 512 + tid];
        }

        // H epilogue: H[w][v] = sigm(D[v][w]) * x[w][v] -> overwrite FPB
#pragma unroll
        for (int t2 = 0; t2 < 2; ++t2) {
            const f32x16& acc = t2 ? accB : accA;
            int m0 = (rt0 + t2) * 32;
#pragma unroll
            for (int q = 0; q < 4; ++q) {
                int v0 = m0 + (q << 3) + (lh << 2);
                u16x4 xv = *(const u16x4*)(lds + XBo + swz(colg, v0 * 2));
                u16x4 v;
#pragma unroll
                for (int e = 0; e < 4; ++e)
                    v[e] = f2bf(sigm(acc[q * 4 + e]) * bf2f(xv[e]));
                *(u16x4*)(lds + FPB + swz(colg, v0 * 2)) = v;
            }
        }
        __syncthreads();   // (5) H ready

        // ===== E: out = H @ Wo0 + V @ Wo2 + xb @ Wsc2 + bout2
#pragma unroll
        for (int i = 0; i < 16; ++i) { accA[i] = 0.f; accB[i] = 0.f; }
#pragma unroll
        for (int kk = 0; kk < 24; ++kk) {
            const ushort_t* pk = (kk < 8) ? pO0 : ((kk < 16) ? pO2 : pS2);
            const int abase = (kk < 8) ? FPB : ((kk < 16) ? FGT : XBo);
            const int kkl = kk & 7;
            bf16x8 b  = *(const bf16x8*)(pk + (((ct * 8 + kkl) * 64 + l) << 3));
            bf16x8 a0 = *(const bf16x8*)(lds + abase + swz(rt0 * 32 + ln,      kkl * 32 + lh * 16));
            bf16x8 a1 = *(const bf16x8*)(lds + abase + swz(rt0 * 32 + 32 + ln, kkl * 32 + lh * 16));
            accA = __builtin_amdgcn_mfma_f32_32x32x16_bf16(a0, b, accA, 0, 0, 0);
            accB = __builtin_amdgcn_mfma_f32_32x32x16_bf16(a1, b, accB, 0, 0, 0);
        }
        {
            long obase = (long)s * 16384;
#pragma unroll
            for (int t2 = 0; t2 < 2; ++t2) {
                const f32x16& acc = t2 ? accB : accA;
                int m0 = (rt0 + t2) * 32;
#pragma unroll
                for (int r = 0; r < 16; ++r) {
                    int row = m0 + (r & 3) + ((r >> 2) << 3) + (lh << 2);
                    out[obase + row * 128 + colg] = acc[r] + biasO;
                }
            }
        }

        // write chunk1 of next x into FPT region (rows 64..127)
        if (it + 1 < spb) {
#pragma unroll
            for (int q = 0; q < 4; ++q) {
                int row = 64 + q * 16 + srow;
                u16x4 v;
                v[0] = f2bf(pf[q].x); v[1] = f2bf(pf[q].y);
                v[2] = f2bf(pf[q].z); v[3] = f2bf(pf[q].w);
                *(u16x4*)(lds + FPTo + swz(row, scb)) = v;
            }
        }
        __syncthreads();   // (6) E's XB reads + next-x staging done
    }
}

extern "C" void kernel_launch(void* const* d_in, const int* in_sizes, int n_in,
                              void* d_out, int out_size, void* d_ws, size_t ws_size,
                              hipStream_t stream) {
    const float* x       = (const float*)d_in[0];
    const float* w_theta = (const float*)d_in[1];
    const float* b_theta = (const float*)d_in[2];
    const float* w_phi   = (const float*)d_in[3];
    const float* b_phi   = (const float*)d_in[4];
    const float* w_g     = (const float*)d_in[5];
    const float* b_g     = (const float*)d_in[6];
    const float* w_sc    = (const float*)d_in[7];
    const float* b_sc    = (const float*)d_in[8];
    const float* w_out   = (const float*)d_in[9];
    const float* b_out   = (const float*)d_in[10];
    float* out = (float*)d_out;

    float* wsc2 = (float*)d_ws;                                        // 128*128 f32
    ushort_t* packs = (ushort_t*)((char*)d_ws + 65536);                // 6*16384 bf16
    float* bout2 = (float*)((char*)d_ws + 65536 + 6 * 16384 * 2);      // 128 f32

    int NS = in_sizes[0] / 16384;   // 2048 strips
    int spb = NS / 256;             // strips per block (8)
    if (spb < 1) spb = 1;
    int grid = (NS + spb - 1) / spb;

    prep_combine<<<128, 128, 0, stream>>>(w_sc, b_sc, w_out, b_out, wsc2, bout2);
    prep_pack<<<6, 256, 0, stream>>>(w_theta, w_phi, w_g, w_out, wsc2, packs);
    cab_main<<<grid, 512, 0, stream>>>(x, b_theta, b_phi, b_g, packs, bout2, out, NS, spb);
}

// Round 6
// 257.635 us; speedup vs baseline: 1.8467x; 1.5059x over previous
//
#include <hip/hip_runtime.h>

// ContextAttentionBlock fused kernel for gfx950.
// Per (b,h) row-strip (2048 strips of [128x128]): everything in LDS with
// bf16 MFMA (32x32x16), fp32 accum. Shortcut conv folded into the output
// projection (w_sc @ Wo1 precomputed).
//
// Occupancy/VGPR notes (measured R1-R5):
//  - hipcc allocates VGPR = 65536/blockDim regardless of launch_bounds arg2
//    (512thr->128, 1024thr->64). We must FIT in 128.
//  - Full unroll of the 8-deep kk MFMA loops hoists ~96 regs of fragment
//    loads -> ~40-reg spill (FETCH 502MB vs 134 ideal, fill-read ~3x).
//    Fix: #pragma unroll 2 bounds the in-flight window to ~24 regs.
//  - LDS rotation: FPT region is dead after phase C, so next strip's x is
//    staged there; XB/FPT roles swap each iteration.

typedef __bf16 bf16x8 __attribute__((ext_vector_type(8)));
typedef float f32x16 __attribute__((ext_vector_type(16)));
typedef unsigned short u16x4 __attribute__((ext_vector_type(4)));
typedef unsigned short ushort_t;

__device__ __forceinline__ unsigned short f2bf(float x) {
    unsigned int u = __float_as_uint(x);
    u += 0x7fffu + ((u >> 16) & 1u);   // round-to-nearest-even
    return (unsigned short)(u >> 16);
}
__device__ __forceinline__ float bf2f(unsigned short h) {
    return __uint_as_float(((unsigned int)h) << 16);
}
// byte offset inside a [128][128] bf16 buffer (256 B rows).
// XOR of row bits into byte-offset bits 4..7 spreads 32-consecutive-row
// column accesses over 16 distinct 16B slots -> ~2-way bank aliasing.
// (R2: conflicts 13.1M -> 2.6M vs the (row&7) variant.)
__device__ __forceinline__ int swz(int row, int cb) {
    return (row << 8) + (cb ^ ((row & 15) << 4));
}
__device__ __forceinline__ float sigm(float t) {
    return 1.0f / (1.0f + __expf(-t));
}

// ---------------- pre-pass 1: combined shortcut weight -----------------
__global__ void prep_combine(const float* __restrict__ w_sc,
                             const float* __restrict__ b_sc,
                             const float* __restrict__ w_out,
                             const float* __restrict__ b_out,
                             float* __restrict__ wsc2,
                             float* __restrict__ bout2) {
    int k = blockIdx.x;      // 0..127
    int n = threadIdx.x;     // 0..127
    float acc = 0.f;
    for (int c = 0; c < 128; ++c)
        acc += w_sc[k * 128 + c] * w_out[(128 + c) * 128 + n];
    wsc2[k * 128 + n] = acc;
    if (k == 0) {
        float b = b_out[n];
        for (int c = 0; c < 128; ++c)
            b += b_sc[c] * w_out[(128 + c) * 128 + n];
        bout2[n] = b;
    }
}

// ---------------- pre-pass 2: pack weights into MFMA B-frag order ------
__global__ void prep_pack(const float* __restrict__ wth,
                          const float* __restrict__ wph,
                          const float* __restrict__ wg,
                          const float* __restrict__ wout,
                          const float* __restrict__ wsc2,
                          ushort_t* __restrict__ packs) {
    int m = blockIdx.x;
    const float* src;
    int rowoff = 0;
    if (m == 0) src = wth;
    else if (m == 1) src = wph;
    else if (m == 2) src = wg;
    else if (m == 3) { src = wout; rowoff = 0; }
    else if (m == 4) { src = wout; rowoff = 256; }
    else src = wsc2;
    ushort_t* dst = packs + m * 16384;
    for (int i = threadIdx.x; i < 16384; i += blockDim.x) {
        int j = i & 7;
        int lane = (i >> 3) & 63;
        int kk = (i >> 9) & 7;
        int nt = i >> 12;
        int k = kk * 16 + ((lane >> 5) << 3) + j;
        int n = nt * 32 + (lane & 31);
        dst[i] = f2bf(src[(rowoff + k) * 128 + n]);
    }
}

// ---------------- main fused kernel ------------------------------------
#define FPB 32768
#define FGT 98304

__global__ __launch_bounds__(512, 2)
void cab_main(const float* __restrict__ x,
              const float* __restrict__ b_theta,
              const float* __restrict__ b_phi,
              const float* __restrict__ b_g,
              const ushort_t* __restrict__ packs,
              const float* __restrict__ bout2,
              float* __restrict__ out,
              int nstrips, int spb) {
    __shared__ __align__(16) char lds[131072];

    const int tid = threadIdx.x;
    const int l   = tid & 63;
    const int wv  = tid >> 6;          // 0..7
    const int ct  = wv & 3;            // tile col (0..3)
    const int rt0 = (wv >> 2) << 1;    // tile rows rt0, rt0+1
    const int ln  = l & 31;
    const int lh  = l >> 5;
    const int colg = ct * 32 + ln;     // this wave's output column

    const ushort_t* pTH = packs;
    const ushort_t* pPH = packs + 16384;
    const ushort_t* pG  = packs + 2 * 16384;
    const ushort_t* pO0 = packs + 3 * 16384;
    const ushort_t* pO2 = packs + 4 * 16384;
    const ushort_t* pS2 = packs + 5 * 16384;

    const float biasTH = b_theta[colg];
    const float biasPH = b_phi[colg];
    const float biasG  = b_g[colg];
    const float biasO  = bout2[colg];

    const int s0 = blockIdx.x * spb;
    if (s0 >= nstrips) return;
    const float4* x4 = (const float4*)x;

    // staging geometry: idx = q*512+tid covers float4 idx -> row=idx>>5,
    // cb = (tid&31)*8 bytes; chunk c covers rows c*64..c*64+63
    const int srow = tid >> 5;          // 0..15
    const int scb  = (tid & 31) * 8;    // byte col

    float4 pf[4];

    // initial full stage of strip s0 into region 0
    {
        long base = (long)s0 * 4096;
#pragma unroll
        for (int c = 0; c < 2; ++c) {
#pragma unroll
            for (int q = 0; q < 4; ++q) pf[q] = x4[base + (c * 4 + q) * 512 + tid];
#pragma unroll
            for (int q = 0; q < 4; ++q) {
                int row = c * 64 + q * 16 + srow;
                u16x4 v;
                v[0] = f2bf(pf[q].x); v[1] = f2bf(pf[q].y);
                v[2] = f2bf(pf[q].z); v[3] = f2bf(pf[q].w);
                *(u16x4*)(lds + swz(row, scb)) = v;
            }
        }
    }
    __syncthreads();

    for (int it = 0; it < spb; ++it) {
        const int s = s0 + it;
        // rotating roles: XB holds current x; FPT region doubles as next-XB
        const int XBo  = (it & 1) ? 65536 : 0;
        const int FPTo = 65536 - XBo;
        f32x16 accA, accB;

        // ===== B1: f_phi = xb @ w_phi + b  -> FPB (row-major) + FPT ([c][w])
#pragma unroll
        for (int i = 0; i < 16; ++i) { accA[i] = 0.f; accB[i] = 0.f; }
#pragma unroll 2
        for (int kk = 0; kk < 8; ++kk) {
            bf16x8 b  = *(const bf16x8*)(pPH + (((ct * 8 + kk) * 64 + l) << 3));
            bf16x8 a0 = *(const bf16x8*)(lds + XBo + swz(rt0 * 32 + ln,      kk * 32 + lh * 16));
            bf16x8 a1 = *(const bf16x8*)(lds + XBo + swz(rt0 * 32 + 32 + ln, kk * 32 + lh * 16));
            accA = __builtin_amdgcn_mfma_f32_32x32x16_bf16(a0, b, accA, 0, 0, 0);
            accB = __builtin_amdgcn_mfma_f32_32x32x16_bf16(a1, b, accB, 0, 0, 0);
        }
#pragma unroll
        for (int t2 = 0; t2 < 2; ++t2) {
            const f32x16& acc = t2 ? accB : accA;
            int m0 = (rt0 + t2) * 32;
#pragma unroll
            for (int r = 0; r < 16; ++r) {
                int row = m0 + (r & 3) + ((r >> 2) << 3) + (lh << 2);
                *(ushort_t*)(lds + FPB + swz(row, colg * 2)) = f2bf(acc[r] + biasPH);
            }
#pragma unroll
            for (int q = 0; q < 4; ++q) {
                int w0 = m0 + (q << 3) + (lh << 2);
                u16x4 v;
#pragma unroll
                for (int e = 0; e < 4; ++e) v[e] = f2bf(acc[q * 4 + e] + biasPH);
                *(u16x4*)(lds + FPTo + swz(colg, w0 * 2)) = v;
            }
        }

        // ===== B2: f_g = xb @ w_g + b -> FGT ([c][w])
#pragma unroll
        for (int i = 0; i < 16; ++i) { accA[i] = 0.f; accB[i] = 0.f; }
#pragma unroll 2
        for (int kk = 0; kk < 8; ++kk) {
            bf16x8 b  = *(const bf16x8*)(pG + (((ct * 8 + kk) * 64 + l) << 3));
            bf16x8 a0 = *(const bf16x8*)(lds + XBo + swz(rt0 * 32 + ln,      kk * 32 + lh * 16));
            bf16x8 a1 = *(const bf16x8*)(lds + XBo + swz(rt0 * 32 + 32 + ln, kk * 32 + lh * 16));
            accA = __builtin_amdgcn_mfma_f32_32x32x16_bf16(a0, b, accA, 0, 0, 0);
            accB = __builtin_amdgcn_mfma_f32_32x32x16_bf16(a1, b, accB, 0, 0, 0);
        }
#pragma unroll
        for (int t2 = 0; t2 < 2; ++t2) {
            const f32x16& acc = t2 ? accB : accA;
            int m0 = (rt0 + t2) * 32;
#pragma unroll
            for (int q = 0; q < 4; ++q) {
                int w0 = m0 + (q << 3) + (lh << 2);
                u16x4 v;
#pragma unroll
                for (int e = 0; e < 4; ++e) v[e] = f2bf(acc[q * 4 + e] + biasG);
                *(u16x4*)(lds + FGT + swz(colg, w0 * 2)) = v;
            }
        }
        __syncthreads();   // (1) FPB/FPT/FGT ready

        // issue chunk0 of next strip's x (latency hidden by D/V/B3/C)
        if (it + 1 < spb) {
            long base = (long)(s + 1) * 4096;
#pragma unroll
            for (int q = 0; q < 4; ++q) pf[q] = x4[base + q * 512 + tid];
        }

        // ===== D: v-logits  D[j][i] = sum_w fp[w][j] * fg[w][i]
#pragma unroll
        for (int i = 0; i < 16; ++i) { accA[i] = 0.f; accB[i] = 0.f; }
#pragma unroll 2
        for (int kk = 0; kk < 8; ++kk) {
            bf16x8 b  = *(const bf16x8*)(lds + FGT + swz(colg, kk * 32 + lh * 16));
            bf16x8 a0 = *(const bf16x8*)(lds + FPTo + swz(rt0 * 32 + ln,      kk * 32 + lh * 16));
            bf16x8 a1 = *(const bf16x8*)(lds + FPTo + swz(rt0 * 32 + 32 + ln, kk * 32 + lh * 16));
            accA = __builtin_amdgcn_mfma_f32_32x32x16_bf16(a0, b, accA, 0, 0, 0);
            accB = __builtin_amdgcn_mfma_f32_32x32x16_bf16(a1, b, accB, 0, 0, 0);
        }
        __syncthreads();   // (2) all D reads of FPT/FGT done

        // V epilogue: V[i][j] = sigm(D[j][i]) * x[i][j]  -> overwrite FGT
#pragma unroll
        for (int t2 = 0; t2 < 2; ++t2) {
            const f32x16& acc = t2 ? accB : accA;
            int m0 = (rt0 + t2) * 32;
#pragma unroll
            for (int q = 0; q < 4; ++q) {
                int j0 = m0 + (q << 3) + (lh << 2);
                u16x4 xv = *(const u16x4*)(lds + XBo + swz(colg, j0 * 2));
                u16x4 v;
#pragma unroll
                for (int e = 0; e < 4; ++e)
                    v[e] = f2bf(sigm(acc[q * 4 + e]) * bf2f(xv[e]));
                *(u16x4*)(lds + FGT + swz(colg, j0 * 2)) = v;
            }
        }

        // ===== B3: f_theta = xb @ w_theta + b -> FPT slot (row-major "ftb")
#pragma unroll
        for (int i = 0; i < 16; ++i) { accA[i] = 0.f; accB[i] = 0.f; }
#pragma unroll 2
        for (int kk = 0; kk < 8; ++kk) {
            bf16x8 b  = *(const bf16x8*)(pTH + (((ct * 8 + kk) * 64 + l) << 3));
            bf16x8 a0 = *(const bf16x8*)(lds + XBo + swz(rt0 * 32 + ln,      kk * 32 + lh * 16));
            bf16x8 a1 = *(const bf16x8*)(lds + XBo + swz(rt0 * 32 + 32 + ln, kk * 32 + lh * 16));
            accA = __builtin_amdgcn_mfma_f32_32x32x16_bf16(a0, b, accA, 0, 0, 0);
            accB = __builtin_amdgcn_mfma_f32_32x32x16_bf16(a1, b, accB, 0, 0, 0);
        }
#pragma unroll
        for (int t2 = 0; t2 < 2; ++t2) {
            const f32x16& acc = t2 ? accB : accA;
            int m0 = (rt0 + t2) * 32;
#pragma unroll
            for (int r = 0; r < 16; ++r) {
                int row = m0 + (r & 3) + ((r >> 2) << 3) + (lh << 2);
                *(ushort_t*)(lds + FPTo + swz(row, colg * 2)) = f2bf(acc[r] + biasTH);
            }
        }
        __syncthreads();   // (3) V + ftb ready

        // ===== C: h-logits  D[v][w] = sum_c ft[v][c] * fp[w][c]
#pragma unroll
        for (int i = 0; i < 16; ++i) { accA[i] = 0.f; accB[i] = 0.f; }
#pragma unroll 2
        for (int kk = 0; kk < 8; ++kk) {
            bf16x8 b  = *(const bf16x8*)(lds + FPB + swz(colg, kk * 32 + lh * 16));
            bf16x8 a0 = *(const bf16x8*)(lds + FPTo + swz(rt0 * 32 + ln,      kk * 32 + lh * 16));
            bf16x8 a1 = *(const bf16x8*)(lds + FPTo + swz(rt0 * 32 + 32 + ln, kk * 32 + lh * 16));
            accA = __builtin_amdgcn_mfma_f32_32x32x16_bf16(a0, b, accA, 0, 0, 0);
            accB = __builtin_amdgcn_mfma_f32_32x32x16_bf16(a1, b, accB, 0, 0, 0);
        }
        __syncthreads();   // (4) all C reads of FPB/FPT done; FPT region now free

        // write chunk0 of next x into FPT region (= next iteration's XB)
        if (it + 1 < spb) {
#pragma unroll
            for (int q = 0; q < 4; ++q) {
                int row = q * 16 + srow;     // rows 0..63
                u16x4 v;
                v[0] = f2bf(pf[q].x); v[1] = f2bf(pf[q].y);
                v[2] = f2bf(pf[q].z); v[3] = f2bf(pf[q].w);
                *(u16x4*)(lds + FPTo + swz(row, scb)) = v;
            }
            // issue chunk1 loads (latency hidden by H epilogue + E)
            long base = (long)(s + 1) * 4096;
#pragma unroll
            for (int q = 0; q < 4; ++q) pf[q] = x4[base + (4 + q) * 512 + tid];
        }

        // H epilogue: H[w][v] = sigm(D[v][w]) * x[w][v] -> overwrite FPB
#pragma unroll
        for (int t2 = 0; t2 < 2; ++t2) {
            const f32x16& acc = t2 ? accB : accA;
            int m0 = (rt0 + t2) * 32;
#pragma unroll
            for (int q = 0; q < 4; ++q) {
                int v0 = m0 + (q << 3) + (lh << 2);
                u16x4 xv = *(const u16x4*)(lds + XBo + swz(colg, v0 * 2));
                u16x4 v;
#pragma unroll
                for (int e = 0; e < 4; ++e)
                    v[e] = f2bf(sigm(acc[q * 4 + e]) * bf2f(xv[e]));
                *(u16x4*)(lds + FPB + swz(colg, v0 * 2)) = v;
            }
        }
        __syncthreads();   // (5) H ready

        // ===== E: out = H @ Wo0 + V @ Wo2 + xb @ Wsc2 + bout2
        //        (three clean 8-loops; acc carries across all 24 steps)
#pragma unroll
        for (int i = 0; i < 16; ++i) { accA[i] = 0.f; accB[i] = 0.f; }
#pragma unroll 2
        for (int kk = 0; kk < 8; ++kk) {
            bf16x8 b  = *(const bf16x8*)(pO0 + (((ct * 8 + kk) * 64 + l) << 3));
            bf16x8 a0 = *(const bf16x8*)(lds + FPB + swz(rt0 * 32 + ln,      kk * 32 + lh * 16));
            bf16x8 a1 = *(const bf16x8*)(lds + FPB + swz(rt0 * 32 + 32 + ln, kk * 32 + lh * 16));
            accA = __builtin_amdgcn_mfma_f32_32x32x16_bf16(a0, b, accA, 0, 0, 0);
            accB = __builtin_amdgcn_mfma_f32_32x32x16_bf16(a1, b, accB, 0, 0, 0);
        }
#pragma unroll 2
        for (int kk = 0; kk < 8; ++kk) {
            bf16x8 b  = *(const bf16x8*)(pO2 + (((ct * 8 + kk) * 64 + l) << 3));
            bf16x8 a0 = *(const bf16x8*)(lds + FGT + swz(rt0 * 32 + ln,      kk * 32 + lh * 16));
            bf16x8 a1 = *(const bf16x8*)(lds + FGT + swz(rt0 * 32 + 32 + ln, kk * 32 + lh * 16));
            accA = __builtin_amdgcn_mfma_f32_32x32x16_bf16(a0, b, accA, 0, 0, 0);
            accB = __builtin_amdgcn_mfma_f32_32x32x16_bf16(a1, b, accB, 0, 0, 0);
        }
#pragma unroll 2
        for (int kk = 0; kk < 8; ++kk) {
            bf16x8 b  = *(const bf16x8*)(pS2 + (((ct * 8 + kk) * 64 + l) << 3));
            bf16x8 a0 = *(const bf16x8*)(lds + XBo + swz(rt0 * 32 + ln,      kk * 32 + lh * 16));
            bf16x8 a1 = *(const bf16x8*)(lds + XBo + swz(rt0 * 32 + 32 + ln, kk * 32 + lh * 16));
            accA = __builtin_amdgcn_mfma_f32_32x32x16_bf16(a0, b, accA, 0, 0, 0);
            accB = __builtin_amdgcn_mfma_f32_32x32x16_bf16(a1, b, accB, 0, 0, 0);
        }
        {
            long obase = (long)s * 16384;
#pragma unroll
            for (int t2 = 0; t2 < 2; ++t2) {
                const f32x16& acc = t2 ? accB : accA;
                int m0 = (rt0 + t2) * 32;
#pragma unroll
                for (int r = 0; r < 16; ++r) {
                    int row = m0 + (r & 3) + ((r >> 2) << 3) + (lh << 2);
                    out[obase + row * 128 + colg] = acc[r] + biasO;
                }
            }
        }

        // write chunk1 of next x into FPT region (rows 64..127)
        if (it + 1 < spb) {
#pragma unroll
            for (int q = 0; q < 4; ++q) {
                int row = 64 + q * 16 + srow;
                u16x4 v;
                v[0] = f2bf(pf[q].x); v[1] = f2bf(pf[q].y);
                v[2] = f2bf(pf[q].z); v[3] = f2bf(pf[q].w);
                *(u16x4*)(lds + FPTo + swz(row, scb)) = v;
            }
        }
        __syncthreads();   // (6) E's XB reads + next-x staging done
    }
}

extern "C" void kernel_launch(void* const* d_in, const int* in_sizes, int n_in,
                              void* d_out, int out_size, void* d_ws, size_t ws_size,
                              hipStream_t stream) {
    const float* x       = (const float*)d_in[0];
    const float* w_theta = (const float*)d_in[1];
    const float* b_theta = (const float*)d_in[2];
    const float* w_phi   = (const float*)d_in[3];
    const float* b_phi   = (const float*)d_in[4];
    const float* w_g     = (const float*)d_in[5];
    const float* b_g     = (const float*)d_in[6];
    const float* w_sc    = (const float*)d_in[7];
    const float* b_sc    = (const float*)d_in[8];
    const float* w_out   = (const float*)d_in[9];
    const float* b_out   = (const float*)d_in[10];
    float* out = (float*)d_out;

    float* wsc2 = (float*)d_ws;                                        // 128*128 f32
    ushort_t* packs = (ushort_t*)((char*)d_ws + 65536);                // 6*16384 bf16
    float* bout2 = (float*)((char*)d_ws + 65536 + 6 * 16384 * 2);      // 128 f32

    int NS = in_sizes[0] / 16384;   // 2048 strips
    int spb = NS / 256;             // strips per block (8)
    if (spb < 1) spb = 1;
    int grid = (NS + spb - 1) / spb;

    prep_combine<<<128, 128, 0, stream>>>(w_sc, b_sc, w_out, b_out, wsc2, bout2);
    prep_pack<<<6, 256, 0, stream>>>(w_theta, w_phi, w_g, w_out, wsc2, packs);
    cab_main<<<grid, 512, 0, stream>>>(x, b_theta, b_phi, b_g, packs, bout2, out, NS, spb);
}